// Round 6
// baseline (615.795 us; speedup 1.0000x reference)
//
#include <hip/hip_runtime.h>

#define N_NODES 100000
#define N_EDGES 3200000
#define EMB 128
#define N_GRAPH 1024
#define N_CLASS 10

#define SCAN_B 1024
#define NB_SCAN ((N_NODES + SCAN_B - 1) / SCAN_B)  // 98

typedef unsigned int uint32;
typedef __attribute__((ext_vector_type(8))) short bf16x8;
typedef __attribute__((ext_vector_type(4))) float f32x4;

__device__ inline unsigned short f2bf(float f) {
  unsigned u = __float_as_uint(f);
  u += 0x7fffu + ((u >> 16) & 1u);
  return (unsigned short)(u >> 16);
}
__device__ inline float bf2f(unsigned short s) {
  return __uint_as_float(((unsigned)s) << 16);
}

// ---------------- embedding: x = shape_emb[s] + color_emb[c] + pos_emb[p] ----
__global__ void k_embed(const int* __restrict__ nf, const float* __restrict__ se,
                        const float* __restrict__ ce, const float* __restrict__ pe,
                        unsigned short* __restrict__ X) {
  int gid = blockIdx.x * blockDim.x + threadIdx.x;  // N_NODES*16 threads, 8 elems each
  if (gid >= N_NODES * 16) return;
  int node = gid >> 4;
  int q = (gid & 15) * 8;
  int s = nf[node * 3 + 0];
  int c = nf[node * 3 + 1];
  int p = nf[node * 3 + 2];
  const float* ps = se + s * EMB + q;
  const float* pc = ce + c * EMB + q;
  const float* pp = pe + p * EMB + q;
  float4 a0 = *(const float4*)ps, a1 = *(const float4*)(ps + 4);
  float4 b0 = *(const float4*)pc, b1 = *(const float4*)(pc + 4);
  float4 d0 = *(const float4*)pp, d1 = *(const float4*)(pp + 4);
  float r0 = a0.x + b0.x + d0.x, r1 = a0.y + b0.y + d0.y;
  float r2 = a0.z + b0.z + d0.z, r3 = a0.w + b0.w + d0.w;
  float r4 = a1.x + b1.x + d1.x, r5 = a1.y + b1.y + d1.y;
  float r6 = a1.z + b1.z + d1.z, r7 = a1.w + b1.w + d1.w;
  uint4 o;
  o.x = (uint32)f2bf(r0) | ((uint32)f2bf(r1) << 16);
  o.y = (uint32)f2bf(r2) | ((uint32)f2bf(r3) << 16);
  o.z = (uint32)f2bf(r4) | ((uint32)f2bf(r5) << 16);
  o.w = (uint32)f2bf(r6) | ((uint32)f2bf(r7) << 16);
  *(uint4*)(X + (size_t)node * EMB + q) = o;
}

// ---------------- count + rank into 8-way sharded counters -------------------
__global__ __launch_bounds__(256) void k_rank(const int* __restrict__ dst,
                                              int* __restrict__ degi8,
                                              int* __restrict__ rank) {
  int e = blockIdx.x * blockDim.x + threadIdx.x;
  if (e < N_EDGES) rank[e] = atomicAdd(&degi8[dst[e] * 8 + (e & 7)], 1);
}

// ---------------- block-wise exclusive scan over node totals -----------------
__global__ void k_scan1(const int* __restrict__ degi8, int* __restrict__ offs,
                        int* __restrict__ part) {
  __shared__ int t[SCAN_B];
  int tid = threadIdx.x;
  int gid = blockIdx.x * SCAN_B + tid;
  int v = 0;
  if (gid < N_NODES) {
    int4 a = *(const int4*)(degi8 + (size_t)gid * 8);
    int4 b = *(const int4*)(degi8 + (size_t)gid * 8 + 4);
    v = a.x + a.y + a.z + a.w + b.x + b.y + b.z + b.w;
  }
  t[tid] = v;
  __syncthreads();
  for (int s = 1; s < SCAN_B; s <<= 1) {
    int u = (tid >= s) ? t[tid - s] : 0;
    __syncthreads();
    t[tid] += u;
    __syncthreads();
  }
  if (gid < N_NODES) offs[gid] = t[tid] - v;
  if (tid == SCAN_B - 1) part[blockIdx.x] = t[tid];
}

__global__ void k_scan2(int* __restrict__ part) {
  __shared__ int t[128];
  int tid = threadIdx.x;
  int v = (tid < NB_SCAN) ? part[tid] : 0;
  t[tid] = v;
  __syncthreads();
  for (int s = 1; s < 128; s <<= 1) {
    int u = (tid >= s) ? t[tid - s] : 0;
    __syncthreads();
    t[tid] += u;
    __syncthreads();
  }
  if (tid < NB_SCAN) part[tid] = t[tid] - v;
}

// ---- finalize: offs -> global; degi8 counts -> per-shard global prefixes ----
__global__ void k_fin(int* __restrict__ offs, const int* __restrict__ part,
                      int* __restrict__ degi8, int* __restrict__ degt,
                      float* __restrict__ deginv) {
  int gid = blockIdx.x * blockDim.x + threadIdx.x;
  if (gid >= N_NODES) return;
  int o = offs[gid] + part[gid >> 10];
  offs[gid] = o;
  int4 a = *(const int4*)(degi8 + (size_t)gid * 8);
  int4 b = *(const int4*)(degi8 + (size_t)gid * 8 + 4);
  int c[8] = {a.x, a.y, a.z, a.w, b.x, b.y, b.z, b.w};
  int run = o;
  int p[8];
#pragma unroll
  for (int s = 0; s < 8; ++s) {
    p[s] = run;
    run += c[s];
  }
  int d = run - o;
  degt[gid] = d;
  deginv[gid] = d > 0 ? 1.0f / (float)d : 0.0f;
  int4 pa = {p[0], p[1], p[2], p[3]};
  int4 pb = {p[4], p[5], p[6], p[7]};
  *(int4*)(degi8 + (size_t)gid * 8) = pa;
  *(int4*)(degi8 + (size_t)gid * 8 + 4) = pb;
}

// ---------------- CSR fill, atomic-free --------------------------------------
__global__ __launch_bounds__(256) void k_fill(const int* __restrict__ src,
                                              const int* __restrict__ dst,
                                              const int* __restrict__ pref8,
                                              const int* __restrict__ rank,
                                              int* __restrict__ csr) {
  int e = blockIdx.x * blockDim.x + threadIdx.x;
  if (e < N_EDGES) {
    int pos = pref8[dst[e] * 8 + (e & 7)] + rank[e];
    csr[pos] = src[e];
  }
}

// ---------------- build concatenated bf16 weights: Wcat[j][k], k 0..255 ------
__global__ void k_wcat(const float* __restrict__ wl, const float* __restrict__ wr,
                       unsigned short* __restrict__ wcat) {
  int gid = blockIdx.x * blockDim.x + threadIdx.x;  // 128*256 = 32768
  int j = gid >> 8;
  int k = gid & 255;
  float v = (k < EMB) ? wl[j * EMB + k] : wr[j * EMB + (k - EMB)];
  wcat[gid] = f2bf(v);
}

// ---------------- mean aggregation (CSR, bf16), predicated unroll-16 ---------
__global__ __launch_bounds__(256) void k_agg(const unsigned short* __restrict__ in,
                                             unsigned short* __restrict__ out,
                                             const int* __restrict__ offs,
                                             const int* __restrict__ degt,
                                             const float* __restrict__ deginv,
                                             const int* __restrict__ csr) {
  int wave = threadIdx.x >> 6;
  int lane = threadIdx.x & 63;
  int node = blockIdx.x * 4 + wave;
  int start = offs[node];
  int cnt = degt[node];
  int lo = lane * 2;
  float ax = 0.f, ay = 0.f;
  for (int i = 0; i < cnt; i += 16) {
    uint32 vals[16];
#pragma unroll
    for (int j = 0; j < 16; ++j) {
      int idx = i + j;
      int cl = (idx < cnt) ? idx : (cnt - 1);
      int s = csr[start + cl];
      uint32 v = *(const uint32*)(in + (size_t)s * EMB + lo);
      vals[j] = (idx < cnt) ? v : 0u;
    }
#pragma unroll
    for (int j = 0; j < 16; ++j) {
      ax += __uint_as_float(vals[j] << 16);
      ay += __uint_as_float(vals[j] & 0xffff0000u);
    }
  }
  float di = deginv[node];
  uint32 packed = (uint32)f2bf(ax * di) | ((uint32)f2bf(ay * di) << 16);
  *(uint32*)(out + (size_t)node * EMB + lo) = packed;
}

// ---------------- fused MFMA GEMM: out = relu([A|S] @ WcatT + bias), bf16 ----
__global__ __launch_bounds__(256) void k_gemm(const unsigned short* __restrict__ A,
                                              const unsigned short* __restrict__ S,
                                              const unsigned short* __restrict__ Wcat,
                                              const float* __restrict__ bias,
                                              unsigned short* __restrict__ out) {
  int wid = threadIdx.x >> 6;
  int lane = threadIdx.x & 63;
  int rows0 = blockIdx.x * 64 + wid * 16;
  int r = lane & 15;
  int khalf = lane >> 4;
  int arow = rows0 + r;
  if (arow > N_NODES - 1) arow = N_NODES - 1;
  const unsigned short* Abase = A + (size_t)arow * EMB + khalf * 8;
  const unsigned short* Sbase = S + (size_t)arow * EMB + khalf * 8;

  f32x4 acc[8] = {};
#pragma unroll
  for (int kc = 0; kc < 8; ++kc) {
    const unsigned short* p = (kc < 4) ? (Abase + kc * 32) : (Sbase + (kc - 4) * 32);
    bf16x8 a = *(const bf16x8*)p;
#pragma unroll
    for (int jc = 0; jc < 8; ++jc) {
      bf16x8 b = *(const bf16x8*)(Wcat + (size_t)(jc * 16 + r) * 256 + kc * 32 + khalf * 8);
      acc[jc] = __builtin_amdgcn_mfma_f32_16x16x32_bf16(a, b, acc[jc], 0, 0, 0);
    }
  }

  int rbase = (lane >> 4) * 4;
#pragma unroll
  for (int jc = 0; jc < 8; ++jc) {
    int col = jc * 16 + r;
    float bv = bias[col];
#pragma unroll
    for (int q = 0; q < 4; ++q) {
      int row = rows0 + rbase + q;
      if (row < N_NODES) {
        float v = fmaxf(acc[jc][q] + bv, 0.f);
        out[(size_t)row * EMB + col] = f2bf(v);
      }
    }
  }
}

// ---------------- mean pooling per graph + linear head -----------------------
__global__ void k_pool(const unsigned short* __restrict__ h, const int* __restrict__ batch,
                       const float* __restrict__ lw, const float* __restrict__ lb,
                       float* __restrict__ out) {
  int g = blockIdx.x;
  int tid = threadIdx.x;  // 128
  int lo = 0, hi = N_NODES;
  while (lo < hi) {
    int mid = (lo + hi) >> 1;
    if (batch[mid] < g) lo = mid + 1; else hi = mid;
  }
  int lo2 = lo, hi2 = N_NODES;
  while (lo2 < hi2) {
    int mid = (lo2 + hi2) >> 1;
    if (batch[mid] < g + 1) lo2 = mid + 1; else hi2 = mid;
  }
  float sum = 0.f;
  for (int n = lo; n < lo2; ++n) sum += bf2f(h[(size_t)n * EMB + tid]);
  int cnt = lo2 - lo;
  float pooled = sum / fmaxf((float)cnt, 1.0f);
  __shared__ float pl[EMB];
  pl[tid] = pooled;
  __syncthreads();
  if (tid < N_CLASS) {
    float o = lb[tid];
    for (int d = 0; d < EMB; ++d) o += pl[d] * lw[tid * EMB + d];
    out[g * N_CLASS + tid] = o;
  }
}

extern "C" void kernel_launch(void* const* d_in, const int* in_sizes, int n_in,
                              void* d_out, int out_size, void* d_ws, size_t ws_size,
                              hipStream_t stream) {
  const int* nf = (const int*)d_in[0];
  const int* ei = (const int*)d_in[1];
  const int* batch = (const int*)d_in[2];
  const float* se = (const float*)d_in[3];
  const float* ce = (const float*)d_in[4];
  const float* pe = (const float*)d_in[5];
  const float* w1l = (const float*)d_in[6];
  const float* b1l = (const float*)d_in[7];
  const float* w1r = (const float*)d_in[8];
  const float* w2l = (const float*)d_in[9];
  const float* b2l = (const float*)d_in[10];
  const float* w2r = (const float*)d_in[11];
  const float* linw = (const float*)d_in[12];
  const float* linb = (const float*)d_in[13];
  float* out = (float*)d_out;

  char* ws = (char*)d_ws;
  size_t off = 0;
  auto alloc = [&](size_t bytes) {
    void* p = ws + off;
    off = (off + bytes + 255) & ~(size_t)255;
    return p;
  };
  unsigned short* X = (unsigned short*)alloc((size_t)N_NODES * EMB * 2);
  unsigned short* H = (unsigned short*)alloc((size_t)N_NODES * EMB * 2);
  unsigned short* AGG = (unsigned short*)alloc((size_t)N_NODES * EMB * 2);
  unsigned short* WC1 = (unsigned short*)alloc((size_t)256 * EMB * 2);
  unsigned short* WC2 = (unsigned short*)alloc((size_t)256 * EMB * 2);
  float* deginv = (float*)alloc((size_t)N_NODES * 4);
  int* degi8 = (int*)alloc((size_t)N_NODES * 8 * 4);
  int* degt = (int*)alloc((size_t)N_NODES * 4);
  int* offs = (int*)alloc((size_t)N_NODES * 4);
  int* part = (int*)alloc((size_t)128 * 4);
  int* rank = (int*)alloc((size_t)N_EDGES * 4);
  int* csr = (int*)alloc((size_t)N_EDGES * 4);

  const int* srcv = ei;
  const int* dstv = ei + N_EDGES;

  hipMemsetAsync(degi8, 0, (size_t)N_NODES * 8 * 4, stream);
  k_embed<<<(N_NODES * 16 + 255) / 256, 256, 0, stream>>>(nf, se, ce, pe, X);
  k_rank<<<(N_EDGES + 255) / 256, 256, 0, stream>>>(dstv, degi8, rank);
  k_scan1<<<NB_SCAN, SCAN_B, 0, stream>>>(degi8, offs, part);
  k_scan2<<<1, 128, 0, stream>>>(part);
  k_fin<<<(N_NODES + 255) / 256, 256, 0, stream>>>(offs, part, degi8, degt, deginv);
  k_fill<<<(N_EDGES + 255) / 256, 256, 0, stream>>>(srcv, dstv, degi8, rank, csr);
  k_wcat<<<128, 256, 0, stream>>>(w1l, w1r, WC1);
  k_wcat<<<128, 256, 0, stream>>>(w2l, w2r, WC2);

  k_agg<<<N_NODES / 4, 256, 0, stream>>>(X, AGG, offs, degt, deginv, csr);
  k_gemm<<<(N_NODES + 63) / 64, 256, 0, stream>>>(AGG, X, WC1, b1l, H);
  k_agg<<<N_NODES / 4, 256, 0, stream>>>(H, AGG, offs, degt, deginv, csr);
  k_gemm<<<(N_NODES + 63) / 64, 256, 0, stream>>>(AGG, H, WC2, b2l, X);
  k_pool<<<N_GRAPH, EMB, 0, stream>>>(X, batch, linw, linb, out);
}